// Round 2
// baseline (757.472 us; speedup 1.0000x reference)
//
#include <hip/hip_runtime.h>

#define GX 128
#define NUM_EMB (GX * GX * GX)
#define NBUCKETS 16384   // bucket key = c000 >> 7  (one (iy,iz) row of 128 cells)

// ws layout:
//   [0,      64 KiB)            : bucket counters -> exclusive prefix -> scatter cursors (16384 u32)
//   [64 KiB, 64 KiB + 4*n_pts)  : sorted point indices (u32)

__device__ __forceinline__ int cell_of(const float* __restrict__ x, int p) {
    float xr0 = x[3 * p + 0] * (float)GX;
    float xr1 = x[3 * p + 1] * (float)GX;
    float xr2 = x[3 * p + 2] * (float)GX;
    int i0 = (int)floorf(xr0);
    int i1 = (int)floorf(xr1);
    int i2 = (int)floorf(xr2);
    int c = i0 + (i1 << 7) + (i2 << 14);
    if (c >= NUM_EMB) c = NUM_EMB - 1;
    return c;
}

__global__ void zero_hist_kernel(unsigned* __restrict__ hist) {
    int i = blockIdx.x * 256 + threadIdx.x;
    if (i < NBUCKETS) hist[i] = 0u;
}

__global__ void hist_kernel(const float* __restrict__ x, unsigned* __restrict__ hist, int n) {
    int p = blockIdx.x * 256 + threadIdx.x;
    if (p >= n) return;
    atomicAdd(&hist[cell_of(x, p) >> 7], 1u);
}

// single block, 1024 threads, 16 buckets each: exclusive prefix sum in place
__global__ __launch_bounds__(1024) void scan_kernel(unsigned* __restrict__ hist) {
    __shared__ unsigned part[1024];
    unsigned t = threadIdx.x;
    unsigned base = t * 16;
    unsigned v[16];
    unsigned s = 0;
#pragma unroll
    for (int i = 0; i < 16; ++i) { v[i] = hist[base + i]; s += v[i]; }
    part[t] = s;
    __syncthreads();
    for (int off = 1; off < 1024; off <<= 1) {
        unsigned cur = part[t];
        unsigned add = (t >= (unsigned)off) ? part[t - off] : 0u;
        __syncthreads();
        part[t] = cur + add;
        __syncthreads();
    }
    unsigned excl = (t == 0) ? 0u : part[t - 1];
#pragma unroll
    for (int i = 0; i < 16; ++i) { unsigned tmp = v[i]; hist[base + i] = excl; excl += tmp; }
}

__global__ void scatter_kernel(const float* __restrict__ x, unsigned* __restrict__ cursors,
                               unsigned* __restrict__ sorted, int n) {
    int p = blockIdx.x * 256 + threadIdx.x;
    if (p >= n) return;
    unsigned b = (unsigned)(cell_of(x, p) >> 7);
    unsigned pos = atomicAdd(&cursors[b], 1u);
    sorted[pos] = (unsigned)p;
}

__global__ __launch_bounds__(256) void grid_emb_main_kernel(
    const float* __restrict__ x,
    const float4* __restrict__ emb4,
    const unsigned* __restrict__ sorted,
    float4* __restrict__ out4,
    int n_pts)
{
    int tid = blockIdx.x * 256 + threadIdx.x;
    int i = tid >> 3;   // sorted position
    int g = tid & 7;    // float4 group within the 32-dim row
    if (i >= n_pts) return;
    int p = (int)sorted[i];

    float xr0 = x[3 * p + 0] * (float)GX;
    float xr1 = x[3 * p + 1] * (float)GX;
    float xr2 = x[3 * p + 2] * (float)GX;
    float f0 = floorf(xr0), f1 = floorf(xr1), f2 = floorf(xr2);
    float w0 = xr0 - f0, w1 = xr1 - f1, w2 = xr2 - f2;

    int c000 = (int)f0 + ((int)f1 << 7) + ((int)f2 << 14);
    if (c000 >= NUM_EMB) c000 = NUM_EMB - 1;

    // Reference corner order / clamp semantics (clamp-to-c000, NOT per-axis):
    int c[8];
    c[0] = c000;                       // v000
    c[1] = c000 + 1;                   // v001  (weight m0*m1*w2)
    c[2] = c000 + GX;                  // v010  (m0*w1*m2)
    c[3] = c000 + GX * GX;             // v100  (w0*m1*m2)
    c[4] = c000 + GX + 1;              // v011  (m0*w1*w2)
    c[5] = c000 + GX * GX + 1;         // v101  (w0*m1*w2)
    c[6] = c000 + GX * GX + GX;        // v110  (w0*w1*m2)
    c[7] = c000 + GX * GX + GX + 1;    // v111  (w0*w1*w2)
#pragma unroll
    for (int k = 1; k < 8; ++k) c[k] = (c[k] >= NUM_EMB) ? c000 : c[k];

    float m0 = 1.f - w0, m1 = 1.f - w1, m2 = 1.f - w2;
    float wt[8];
    wt[0] = m0 * m1 * m2;
    wt[1] = m0 * m1 * w2;
    wt[2] = m0 * w1 * m2;
    wt[3] = w0 * m1 * m2;
    wt[4] = m0 * w1 * w2;
    wt[5] = w0 * m1 * w2;
    wt[6] = w0 * w1 * m2;
    wt[7] = w0 * w1 * w2;

    // All 8 gathers issued back-to-back — independent loads, max MLP.
    float4 v[8];
#pragma unroll
    for (int k = 0; k < 8; ++k) v[k] = emb4[c[k] * 8 + g];

    float4 acc;
    acc.x = 0.f; acc.y = 0.f; acc.z = 0.f; acc.w = 0.f;
#pragma unroll
    for (int k = 0; k < 8; ++k) {
        acc.x = fmaf(wt[k], v[k].x, acc.x);
        acc.y = fmaf(wt[k], v[k].y, acc.y);
        acc.z = fmaf(wt[k], v[k].z, acc.z);
        acc.w = fmaf(wt[k], v[k].w, acc.w);
    }

    out4[p * 8 + g] = acc;
}

extern "C" void kernel_launch(void* const* d_in, const int* in_sizes, int n_in,
                              void* d_out, int out_size, void* d_ws, size_t ws_size,
                              hipStream_t stream) {
    const float* x = (const float*)d_in[0];          // (N_PTS, 3) f32
    const float4* emb4 = (const float4*)d_in[1];     // (NUM_EMB, 32) f32 as float4
    float4* out4 = (float4*)d_out;                   // (N_PTS, 32) f32 as float4

    int n_pts = in_sizes[0] / 3;

    unsigned* hist = (unsigned*)d_ws;                        // 16384 u32
    unsigned* sorted = (unsigned*)((char*)d_ws + 65536);     // n_pts u32

    int pblocks = (n_pts + 255) / 256;

    zero_hist_kernel<<<(NBUCKETS + 255) / 256, 256, 0, stream>>>(hist);
    hist_kernel<<<pblocks, 256, 0, stream>>>(x, hist, n_pts);
    scan_kernel<<<1, 1024, 0, stream>>>(hist);
    scatter_kernel<<<pblocks, 256, 0, stream>>>(x, hist, sorted, n_pts);

    int total_threads = n_pts * 8;
    grid_emb_main_kernel<<<(total_threads + 255) / 256, 256, 0, stream>>>(
        x, emb4, sorted, out4, n_pts);
}